// Round 1
// 1171.314 us; speedup vs baseline: 1.2534x; 1.2534x over previous
//
#include <hip/hip_runtime.h>
#include <hip/hip_bf16.h>
#include <math.h>
#include <stdint.h>

typedef __hip_bfloat16 bf16;
typedef __attribute__((ext_vector_type(8))) short short8;
typedef __attribute__((ext_vector_type(4))) short short4v;
typedef __attribute__((ext_vector_type(4))) float f32x4;

#define CC 66      // channels = J*DIMS
#define TT 100     // time steps
#define JJ 22      // joints
#define HH 8       // heads
#define HD 64      // head dim
#define EE 512     // embed
#define CPAD 101   // comb LDS stride in k_epi / k_fused

// padded token layouts in ws (zero-padded so MFMA K-chunks read clean zeros)
#define SPT_R 112  // spT rows (>=100, mult of 16)
#define SPT_S 96   // spT stride (>=66, mult of 32 for k-chunks)
#define TP_R 80    // tp rows (>=66)
#define TP_S 128   // tp stride (>=100)

// weight section offsets (bf16 elements) inside ws
#define W_STWK 0                    // [512][128]
#define W_STWV 65536                // [512][128]
#define W_STWQ 131072               // [512][96]
#define W_STWO 180224               // [80][512]
#define W_TSWK 221184               // [512][96]
#define W_TSWV 270336               // [512][96]
#define W_TSWQ 319488               // [512][128]
#define W_TSWO 385024               // [112][512]
#define W_TOTAL 442368

__device__ __forceinline__ float b2f(bf16 v){ return __bfloat162float(v); }
__device__ __forceinline__ bf16 f2b(float v){ return __float2bfloat16(v); }
__device__ __forceinline__ short sb(float v){ __hip_bfloat16 h = __float2bfloat16(v); return *(short*)&h; }
__device__ __forceinline__ float fb(short s){ __hip_bfloat16 h; *(short*)&h = s; return __bfloat162float(h); }

// ---------------------------------------------------------------- k_tr
__global__ void k_tr(const float* __restrict__ src, bf16* __restrict__ dst,
                     int Rsrc, int Csrc, int JP, int IP)
{
  int o = blockIdx.x*256 + threadIdx.x;
  if (o >= JP*IP) return;
  int j = o / IP, i = o - j*IP;
  float v = (j < Csrc && i < Rsrc) ? src[(long)i*Csrc + j] : 0.f;
  dst[o] = f2b(v);
}

// ---------------------------------------------------------------- k_prep
__global__ __launch_bounds__(256) void k_prep(
    const float* __restrict__ x, const float* __restrict__ adj,
    const float* __restrict__ sadj, const float* __restrict__ tmask,
    const float* __restrict__ tadj,
    bf16* __restrict__ spT_all, bf16* __restrict__ tp_all)
{
  __shared__ float s_x[CC*TT];
  __shared__ float s_Mt[TT*TT];
  __shared__ float s_A[JJ*JJ];
  __shared__ float s_dis[JJ];
  const int b = blockIdx.x, tid = threadIdx.x;
  const long bb = (long)b * (CC*TT);

  if (tid < JJ) {
    float dsum = 0.f;
    for (int i = 0; i < JJ; ++i) dsum += adj[tid*JJ + i];
    s_dis[tid] = dsum > 0.f ? rsqrtf(dsum) : 0.f;
  }
  for (int o = tid; o < CC*TT; o += 256) s_x[o] = x[bb + o];
  for (int o = tid; o < TT*TT; o += 256) {
    int f = o / TT, t = o - f*TT;
    s_Mt[t*TT + f] = tadj[o] * tmask[o];
  }
  __syncthreads();
  for (int o = tid; o < JJ*JJ; o += 256) {
    int v = o / JJ, j = o - v*JJ;
    s_A[o] = sadj[o] * adj[o] * s_dis[v] * s_dis[j];
  }
  __syncthreads();

  bf16* spT = spT_all + (long)b * (SPT_R*SPT_S);
  bf16* tp  = tp_all  + (long)b * (TP_R*TP_S);

  for (int o = tid; o < SPT_R*SPT_S; o += 256) {
    int t = o / SPT_S, c = o - t*SPT_S;
    float acc = 0.f;
    if (t < TT && c < CC) {
      int v = c / 3, dd = c - v*3;
      for (int j = 0; j < JJ; ++j) acc += s_A[v*JJ + j] * s_x[(j*3 + dd)*TT + t];
    }
    spT[o] = f2b(acc);
  }
  for (int o = tid; o < TP_R*TP_S; o += 256) {
    int n = o / TP_S, f = o - n*TP_S;
    float acc = 0.f;
    if (n < CC && f < TT) {
      float a0 = 0.f, a1 = 0.f;
      for (int t = 0; t < TT; t += 2) {
        a0 += s_x[n*TT + t    ] * s_Mt[(t    )*TT + f];
        a1 += s_x[n*TT + t + 1] * s_Mt[(t + 1)*TT + f];
      }
      acc = a0 + a1;
    }
    tp[o] = f2b(acc);
  }
}

// ---------------------------------------------------------------- MFMA helper
// Fully compile-time tile counts / K-chunks -> fully unrolled, loads batch up.
// A[m=lane&15][k=quad*8+j]; B[n=lane&15][k=quad*8+j]; D col=lane&15,row=quad*4+reg.
template<int Mt, int Nt, int KCH>
__device__ __forceinline__ void mm_tiles_t(
    const short* __restrict__ A, int sA,
    const short* __restrict__ Bm, int sB,
    short* __restrict__ D, int sD,
    const float* __restrict__ bias, float scale,
    int wave, int ln, int qd)
{
  constexpr int NTILE = Mt*Nt;
  constexpr int NU = (NTILE + 7) / 8;
  #pragma unroll
  for (int u = 0; u < NU; ++u) {
    int ti = u*8 + wave;
    if (ti < NTILE) {
      int mi = ti / Nt, ni = ti - mi*Nt;
      f32x4 acc = {0.f, 0.f, 0.f, 0.f};
      const short* ap = A  + (long)(mi*16 + ln)*sA + qd*8;
      const short* bp = Bm + (long)(ni*16 + ln)*sB + qd*8;
      #pragma unroll
      for (int kc = 0; kc < KCH; ++kc) {
        short8 af = *(const short8*)(ap + kc*32);
        short8 bf = *(const short8*)(bp + kc*32);
        acc = __builtin_amdgcn_mfma_f32_16x16x32_bf16(af, bf, acc, 0, 0, 0);
      }
      int col = ni*16 + ln;
      float bv_ = bias ? bias[col] : 0.f;
      short* dp = D + (mi*16 + qd*4)*sD + col;
      #pragma unroll
      for (int r = 0; r < 4; ++r) dp[r*sD] = sb((acc[r] + bv_) * scale);
    }
  }
}

// ---------------------------------------------------------------- attn body
// A=0: q = spatial tokens (100), kv = temporal (66)
// A=1: q = temporal tokens (66), kv = spatial (100)
// PLAIN: non-atomic stores to per-flavor buffers; else atomicAdd into comb_g.
template<int A, bool PLAIN>
__device__ __forceinline__ void attn_body(
    short* __restrict__ Km, short* __restrict__ VTm,
    short* __restrict__ Qm, short* __restrict__ Pm,
    const bf16* __restrict__ spT_all, const bf16* __restrict__ tp_all,
    const bf16* __restrict__ wsec,
    const float* __restrict__ st_bq, const float* __restrict__ st_bv,
    const float* __restrict__ ts_bq, const float* __restrict__ ts_bv,
    float* __restrict__ o1, float* __restrict__ o2, float* __restrict__ comb_g)
{
  constexpr int QROWS = A ? 66 : 100;
  constexpr int KROWS = A ? 100 : 66;
  constexpr int MQ  = A ? 5 : 7;
  constexpr int MK  = A ? 7 : 5;
  constexpr int QCH = A ? 4 : 3;   // q-projection k-chunks
  constexpr int KCH = A ? 3 : 4;   // k/v-projection k-chunks
  constexpr int PCH = A ? 4 : 3;   // PV k-chunks
  constexpr int SAQ = A ? TP_S : SPT_S;
  constexpr int SAK = A ? SPT_S : TP_S;

  const int b = blockIdx.x >> 1, tid = threadIdx.x;
  const long bb = (long)b * (CC*TT);
  const int wave = tid >> 6, lane = tid & 63, ln = lane & 15, qd = lane >> 4;

  const short* Aq = (const short*)(A ? (tp_all  + (long)b*TP_R*TP_S)
                                     : (spT_all + (long)b*SPT_R*SPT_S));
  const short* Ak = (const short*)(A ? (spT_all + (long)b*SPT_R*SPT_S)
                                     : (tp_all  + (long)b*TP_R*TP_S));
  const short* wqT = (const short*)(wsec + (A ? W_TSWQ : W_STWQ));
  const short* wkT = (const short*)(wsec + (A ? W_TSWK : W_STWK));
  const short* wvT = (const short*)(wsec + (A ? W_TSWV : W_STWV));
  const short* woT = (const short*)(wsec + (A ? W_TSWO : W_STWO));
  const float* bq = A ? ts_bq : st_bq;
  const float* bv = A ? ts_bv : st_bv;

  // zero-init P and VT pads (correctness depends on pad columns being zero)
  for (int o = tid; o < SPT_R*136; o += 512) Pm[o] = 0;
  for (int o = tid; o < 64*136;   o += 512) VTm[o] = 0;
  __syncthreads();

  constexpr int NU2 = (MQ*MK + 7) / 8;   // 5
  f32x4 accO[NU2];
  { f32x4 z = {0.f,0.f,0.f,0.f}; for (int i = 0; i < NU2; ++i) accO[i] = z; }

  for (int h = 0; h < HH; ++h) {
    const int base = h*HD;
    // builds: all operands global, disjoint LDS outputs -> no inner barriers
    mm_tiles_t<MK, 4, KCH>(Ak, SAK, wkT + (long)base*SAK, SAK, Km, 72,
                           nullptr, 1.f, wave, ln, qd);          // K
    mm_tiles_t<4, MK, KCH>(wvT + (long)base*SAK, SAK, Ak, SAK, VTm, 136,
                           nullptr, 1.f, wave, ln, qd);          // V^T
    mm_tiles_t<MQ, 4, QCH>(Aq, SAQ, wqT + (long)base*SAQ, SAQ, Qm, 72,
                           bq + base, 1.f, wave, ln, qd);        // Q (+bq)
    __syncthreads();
    // S = Q @ K^T * 1/8
    mm_tiles_t<MQ, MK, 2>(Qm, 72, Km, 72, Pm, 136, nullptr, 0.125f, wave, ln, qd);
    __syncthreads();
    // wave-parallel softmax: 4 lanes per row, exp kept in registers
    {
      const int r = tid >> 2, sub = tid & 3;
      constexpr int NCH  = (KROWS + 3) / 4;   // short4 chunks per row
      constexpr int PERL = (NCH + 3) / 4;     // chunks per lane
      if (r < QROWS) {
        short* pr = Pm + r*136;
        float v[PERL*4];
        float mx = -1e30f;
        #pragma unroll
        for (int u = 0; u < PERL; ++u) {
          int j4 = sub + u*4;
          float f0 = -1e30f, f1 = -1e30f, f2 = -1e30f, f3 = -1e30f;
          if (j4 < NCH) {
            short4v q4 = ((const short4v*)pr)[j4];
            int base0 = j4*4;
            f0 = fb(q4.x);
            f1 = (base0+1 < KROWS) ? fb(q4.y) : -1e30f;
            f2 = (base0+2 < KROWS) ? fb(q4.z) : -1e30f;
            f3 = (base0+3 < KROWS) ? fb(q4.w) : -1e30f;
          }
          v[u*4+0]=f0; v[u*4+1]=f1; v[u*4+2]=f2; v[u*4+3]=f3;
          mx = fmaxf(mx, fmaxf(fmaxf(f0,f1), fmaxf(f2,f3)));
        }
        mx = fmaxf(mx, __shfl_xor(mx, 1));
        mx = fmaxf(mx, __shfl_xor(mx, 2));
        float sum = 0.f;
        #pragma unroll
        for (int i = 0; i < PERL*4; ++i) { float p = __expf(v[i]-mx); v[i] = p; sum += p; }
        sum += __shfl_xor(sum, 1);
        sum += __shfl_xor(sum, 2);
        float rs = 1.f / sum;
        #pragma unroll
        for (int u = 0; u < PERL; ++u) {
          int j4 = sub + u*4;
          if (j4 < NCH) {
            short4v w4;
            w4.x = sb(v[u*4+0]*rs); w4.y = sb(v[u*4+1]*rs);
            w4.z = sb(v[u*4+2]*rs); w4.w = sb(v[u*4+3]*rs);
            ((short4v*)pr)[j4] = w4;
          }
        }
      }
    }
    __syncthreads();
    // O = P @ V + bv  (into Qm; Q dead after S)
    mm_tiles_t<MQ, 4, PCH>(Pm, 136, VTm, 136, Qm, 72, bv + base, 1.f, wave, ln, qd);
    __syncthreads();
    // out += O @ wo  (B from global pre-transposed woT, stride 512)
    #pragma unroll
    for (int u = 0; u < NU2; ++u) {
      int ti = u*8 + wave;
      if (ti < MQ*MK) {
        int mi = ti / MK, ni = ti - mi*MK;
        const short* ap = Qm + (mi*16 + ln)*72 + qd*8;
        const short* bp = woT + (long)(ni*16 + ln)*512 + base + qd*8;
        f32x4 acc = accO[u];
        acc = __builtin_amdgcn_mfma_f32_16x16x32_bf16(*(const short8*)ap,
                                                      *(const short8*)bp, acc, 0,0,0);
        acc = __builtin_amdgcn_mfma_f32_16x16x32_bf16(*(const short8*)(ap+32),
                                                      *(const short8*)(bp+32), acc, 0,0,0);
        accO[u] = acc;
      }
    }
    __syncthreads();   // Oproj reads of Qm done before next head's builds write it
  }

  // accumulated out-proj -> per-flavor buffer (plain) or comb (atomic)
  #pragma unroll
  for (int u = 0; u < NU2; ++u) {
    int ti = u*8 + wave;
    if (ti < MQ*MK) {
      int mi = ti / MK, ni = ti - mi*MK;
      int col = ni*16 + ln;
      #pragma unroll
      for (int r = 0; r < 4; ++r) {
        int row = mi*16 + qd*4 + r;
        if (row < QROWS && col < KROWS) {
          if (PLAIN) {
            if (A) o2[bb + (long)row*TT + col]  = accO[u][r];   // [c][t]
            else   o1[bb + (long)row*CC + col]  = accO[u][r];   // [t][c]
          } else {
            long off = A ? ((long)row*TT + col) : ((long)col*TT + row);
            atomicAdd(&comb_g[bb + off], accO[u][r]);
          }
        }
      }
    }
  }
}

// ---------------------------------------------------------------- k_attn
__global__ __launch_bounds__(512) void k_attn(
    const bf16* __restrict__ spT_all, const bf16* __restrict__ tp_all,
    const bf16* __restrict__ wsec,
    const float* __restrict__ st_bq, const float* __restrict__ st_bv,
    const float* __restrict__ ts_bq, const float* __restrict__ ts_bv,
    float* __restrict__ o1, float* __restrict__ o2,
    float* __restrict__ comb_g, int plain)
{
  __shared__ __align__(16) short Km [SPT_R*72];
  __shared__ __align__(16) short VTm[64*136];
  __shared__ __align__(16) short Qm [SPT_R*72];
  __shared__ __align__(16) short Pm [SPT_R*136];
  if (plain) {
    if (blockIdx.x & 1)
      attn_body<1,true >(Km,VTm,Qm,Pm,spT_all,tp_all,wsec,st_bq,st_bv,ts_bq,ts_bv,o1,o2,comb_g);
    else
      attn_body<0,true >(Km,VTm,Qm,Pm,spT_all,tp_all,wsec,st_bq,st_bv,ts_bq,ts_bv,o1,o2,comb_g);
  } else {
    if (blockIdx.x & 1)
      attn_body<1,false>(Km,VTm,Qm,Pm,spT_all,tp_all,wsec,st_bq,st_bv,ts_bq,ts_bv,o1,o2,comb_g);
    else
      attn_body<0,false>(Km,VTm,Qm,Pm,spT_all,tp_all,wsec,st_bq,st_bv,ts_bq,ts_bv,o1,o2,comb_g);
  }
}

// ---------------------------------------------------------------- k_epi
__global__ __launch_bounds__(256) void k_epi(
    const float* __restrict__ comb_g,
    const float* __restrict__ c1, const float* __restrict__ c2,
    const float* __restrict__ x,
    const float* __restrict__ st_bo, const float* __restrict__ ts_bo,
    const float* __restrict__ alpha, const float* __restrict__ beta,
    const float* __restrict__ fcw, const float* __restrict__ fcb,
    float* __restrict__ out, int plain)
{
  __shared__ float s_cb[CC*CPAD];
  __shared__ float s_w[TT*TT];
  const int b = blockIdx.x, tid = threadIdx.x;
  const long bb = (long)b * (CC*TT);

  for (int o = tid; o < CC*TT; o += 256) {
    int c = o / TT, t = o - c*TT;
    float v;
    if (plain) v = c1[bb + (long)t*CC + c] + c2[bb + o];
    else       v = comb_g[bb + o];
    s_cb[c*CPAD + t] = v + st_bo[c] + ts_bo[t];
  }
  for (int o = tid; o < TT*TT; o += 256) {
    int f = o / TT, t = o - f*TT;
    s_w[t*TT + f] = fcw[o];
  }
  __syncthreads();
  if (tid < TT) {
    const int t = tid;
    float mean = 0.f;
    for (int c = 0; c < CC; ++c) mean += s_cb[c*CPAD + t];
    mean *= (1.f/CC);
    float var = 0.f;
    for (int c = 0; c < CC; ++c) { float dv = s_cb[c*CPAD + t] - mean; var += dv*dv; }
    var *= (1.f/CC);
    float rstd = 1.f / sqrtf(var + 1e-5f);
    for (int c = 0; c < CC; ++c) {
      float y = (s_cb[c*CPAD + t] - mean) * rstd * alpha[c] + beta[c];
      s_cb[c*CPAD + t] = y + x[bb + c*TT + t];
    }
  }
  __syncthreads();
  for (int o = tid; o < CC*TT; o += 256) {
    int c = o / TT, f = o - c*TT;
    const float* cr = s_cb + c*CPAD;
    float a0 = 0.f, a1 = 0.f;
    for (int t = 0; t < TT; t += 2) {
      a0 += cr[t    ] * s_w[(t    )*TT + f];
      a1 += cr[t + 1] * s_w[(t + 1)*TT + f];
    }
    out[bb + o] = tanhf(a0 + a1 + fcb[f]);
  }
}

// ---------------------------------------------------------------- R4 fallback
__global__ __launch_bounds__(128) void k_fused(
    const float* __restrict__ x, const float* __restrict__ adj,
    const float* __restrict__ sadj, const float* __restrict__ tmask,
    const float* __restrict__ tadj,
    const float* __restrict__ st_wq, const float* __restrict__ st_bq,
    const float* __restrict__ st_wk, const float* __restrict__ st_bk,
    const float* __restrict__ st_wv, const float* __restrict__ st_bv,
    const float* __restrict__ st_wo, const float* __restrict__ st_bo,
    const float* __restrict__ ts_wq, const float* __restrict__ ts_bq,
    const float* __restrict__ ts_wk, const float* __restrict__ ts_bk,
    const float* __restrict__ ts_wv, const float* __restrict__ ts_bv,
    const float* __restrict__ ts_wo, const float* __restrict__ ts_bo,
    const float* __restrict__ alpha, const float* __restrict__ beta,
    const float* __restrict__ fcw, const float* __restrict__ fcb,
    float* __restrict__ out)
{
  __shared__ float s_sp[CC*TT];
  __shared__ float s_tp[CC*TT];
  __shared__ __align__(16) float s_kv[2*TT*HD];
  __shared__ float s_comb[CC*CPAD];
  __shared__ float s_A[JJ*JJ];
  __shared__ float s_dis[JJ];

  const int b = blockIdx.x, tid = threadIdx.x;
  const long bb = (long)b * (CC*TT);
  float* s_xs = s_comb;
  float* s_Mt = s_kv;

  if (tid < JJ) {
    float dsum = 0.f;
    for (int i = 0; i < JJ; ++i) dsum += adj[tid*JJ + i];
    s_dis[tid] = dsum > 0.f ? rsqrtf(dsum) : 0.f;
  }
  for (int o = tid; o < CC*TT; o += 128) s_xs[o] = x[bb + o];
  for (int o = tid; o < TT*TT; o += 128) {
    int f = o / TT, t = o - f*TT;
    s_Mt[t*TT + f] = tadj[o] * tmask[o];
  }
  __syncthreads();
  for (int o = tid; o < JJ*JJ; o += 128) {
    int v = o / JJ, j = o - v*JJ;
    s_A[o] = sadj[o] * adj[o] * s_dis[v] * s_dis[j];
  }
  __syncthreads();

  for (int o = tid; o < CC*TT; o += 128) {
    int c = o / TT, t = o - c*TT, v = c / 3, dd = c - v*3;
    float acc = 0.f;
    for (int j = 0; j < JJ; ++j) acc += s_A[v*JJ + j] * s_xs[(j*3 + dd)*TT + t];
    s_sp[o] = acc;
  }
  for (int o = tid; o < CC*TT; o += 128) {
    int n = o / TT, f = o - n*TT;
    float a0 = 0.f, a1 = 0.f;
    for (int t = 0; t < TT; t += 2) {
      a0 += s_xs[n*TT + t    ] * s_Mt[(t    )*TT + f];
      a1 += s_xs[n*TT + t + 1] * s_Mt[(t + 1)*TT + f];
    }
    s_tp[o] = a0 + a1;
  }
  __syncthreads();

  for (int o = tid; o < CC*TT; o += 128) {
    int c = o / TT, t = o - c*TT;
    s_comb[c*CPAD + t] = st_bo[c] + ts_bo[t];
  }

  {
    float* s_k = s_kv;
    float* s_v = s_kv + TT*HD;
    for (int h = 0; h < HH; ++h) {
      const int base = h*HD;
      __syncthreads();
      {
        const int d = tid & 63, krow = tid >> 6;
        for (int kk = 0; kk < CC/2; ++kk) {
          int k = kk*2 + krow;
          float aK = st_bk[base + d], aV = st_bv[base + d];
          const float* tr = s_tp + k*TT;
          for (int t = 0; t < TT; ++t) {
            float a = tr[t];
            aK += a * st_wk[(long)t*EE + base + d];
            aV += a * st_wv[(long)t*EE + base + d];
          }
          s_k[k*HD + d] = aK;
          s_v[k*HD + d] = aV;
        }
      }
      __syncthreads();
      if (tid < TT) {
        const int q = tid;
        float qv[HD];
        #pragma unroll
        for (int d = 0; d < HD; ++d) qv[d] = st_bq[base + d];
        for (int c = 0; c < CC; ++c) {
          float a = s_sp[c*TT + q];
          const float* wr = st_wq + (long)c*EE + base;
          #pragma unroll
          for (int d = 0; d < HD; ++d) qv[d] += a * wr[d];
        }
        float m = -INFINITY, l = 0.f, ov[HD];
        #pragma unroll
        for (int d = 0; d < HD; ++d) ov[d] = 0.f;
        for (int k = 0; k < CC; ++k) {
          const float4* kr4 = (const float4*)(s_k + k*HD);
          float s0=0.f,s1=0.f,s2=0.f,s3=0.f;
          #pragma unroll
          for (int i = 0; i < 16; ++i) {
            float4 kk4 = kr4[i];
            s0 += qv[4*i  ]*kk4.x; s1 += qv[4*i+1]*kk4.y;
            s2 += qv[4*i+2]*kk4.z; s3 += qv[4*i+3]*kk4.w;
          }
          float s  = (s0+s1+s2+s3) * 0.125f;
          float mn = fmaxf(m, s);
          float corr = __expf(m - mn);
          float p    = __expf(s - mn);
          l = l*corr + p;
          const float4* vr4 = (const float4*)(s_v + k*HD);
          #pragma unroll
          for (int i = 0; i < 16; ++i) {
            float4 vv4 = vr4[i];
            ov[4*i  ] = ov[4*i  ]*corr + p*vv4.x;
            ov[4*i+1] = ov[4*i+1]*corr + p*vv4.y;
            ov[4*i+2] = ov[4*i+2]*corr + p*vv4.z;
            ov[4*i+3] = ov[4*i+3]*corr + p*vv4.w;
          }
          m = mn;
        }
        float rl = 1.f/l;
        #pragma unroll
        for (int d = 0; d < HD; ++d) ov[d] *= rl;
        for (int c = 0; c < CC; ++c) {
          const float* wr = st_wo + (long)base*CC + c;
          float a0=0.f,a1=0.f,a2=0.f,a3=0.f;
          #pragma unroll
          for (int d = 0; d < HD; d += 4) {
            a0 += ov[d  ]*wr[(long)(d  )*CC]; a1 += ov[d+1]*wr[(long)(d+1)*CC];
            a2 += ov[d+2]*wr[(long)(d+2)*CC]; a3 += ov[d+3]*wr[(long)(d+3)*CC];
          }
          s_comb[c*CPAD + q] += a0+a1+a2+a3;
        }
      }
    }
  }

  {
    float* s_k = s_kv;
    float* s_v = s_kv + TT*HD;
    for (int h = 0; h < HH; ++h) {
      const int base = h*HD;
      __syncthreads();
      {
        const int d = tid & 63, krow = tid >> 6;
        for (int kk = 0; kk < TT/2; ++kk) {
          int k = kk*2 + krow;
          float aK = ts_bk[base + d], aV = ts_bv[base + d];
          for (int c = 0; c < CC; ++c) {
            float a = s_sp[c*TT + k];
            aK += a * ts_wk[(long)c*EE + base + d];
            aV += a * ts_wv[(long)c*EE + base + d];
          }
          s_k[k*HD + d] = aK;
          s_v[k*HD + d] = aV;
        }
      }
      __syncthreads();
      if (tid < CC) {
        const int q = tid;
        float qv[HD];
        #pragma unroll
        for (int d = 0; d < HD; ++d) qv[d] = ts_bq[base + d];
        const float* tr = s_tp + q*TT;
        for (int t = 0; t < TT; ++t) {
          float a = tr[t];
          const float* wr = ts_wq + (long)t*EE + base;
          #pragma unroll
          for (int d = 0; d < HD; ++d) qv[d] += a * wr[d];
        }
        float m = -INFINITY, l = 0.f, ov[HD];
        #pragma unroll
        for (int d = 0; d < HD; ++d) ov[d] = 0.f;
        for (int k = 0; k < TT; ++k) {
          const float4* kr4 = (const float4*)(s_k + k*HD);
          float s0=0.f,s1=0.f,s2=0.f,s3=0.f;
          #pragma unroll
          for (int i = 0; i < 16; ++i) {
            float4 kk4 = kr4[i];
            s0 += qv[4*i  ]*kk4.x; s1 += qv[4*i+1]*kk4.y;
            s2 += qv[4*i+2]*kk4.z; s3 += qv[4*i+3]*kk4.w;
          }
          float s  = (s0+s1+s2+s3) * 0.125f;
          float mn = fmaxf(m, s);
          float corr = __expf(m - mn);
          float p    = __expf(s - mn);
          l = l*corr + p;
          const float4* vr4 = (const float4*)(s_v + k*HD);
          #pragma unroll
          for (int i = 0; i < 16; ++i) {
            float4 vv4 = vr4[i];
            ov[4*i  ] = ov[4*i  ]*corr + p*vv4.x;
            ov[4*i+1] = ov[4*i+1]*corr + p*vv4.y;
            ov[4*i+2] = ov[4*i+2]*corr + p*vv4.z;
            ov[4*i+3] = ov[4*i+3]*corr + p*vv4.w;
          }
          m = mn;
        }
        float rl = 1.f/l;
        #pragma unroll
        for (int d = 0; d < HD; ++d) ov[d] *= rl;
        for (int t = 0; t < TT; ++t) {
          const float* wr = ts_wo + (long)base*TT + t;
          float a0=0.f,a1=0.f,a2=0.f,a3=0.f;
          #pragma unroll
          for (int d = 0; d < HD; d += 4) {
            a0 += ov[d  ]*wr[(long)(d  )*TT]; a1 += ov[d+1]*wr[(long)(d+1)*TT];
            a2 += ov[d+2]*wr[(long)(d+2)*TT]; a3 += ov[d+3]*wr[(long)(d+3)*TT];
          }
          s_comb[q*CPAD + t] += a0+a1+a2+a3;
        }
      }
    }
  }
  __syncthreads();

  if (tid < TT) {
    const int t = tid;
    float mean = 0.f;
    for (int c = 0; c < CC; ++c) mean += s_comb[c*CPAD + t];
    mean *= (1.f/CC);
    float var = 0.f;
    for (int c = 0; c < CC; ++c) { float dv = s_comb[c*CPAD + t] - mean; var += dv*dv; }
    var *= (1.f/CC);
    float rstd = 1.f / sqrtf(var + 1e-5f);
    for (int c = 0; c < CC; ++c) {
      float y = (s_comb[c*CPAD + t] - mean) * rstd * alpha[c] + beta[c];
      s_comb[c*CPAD + t] = y + x[bb + c*TT + t];
    }
  }
  __syncthreads();

  float* s_w = s_kv;
  for (int o = tid; o < TT*TT; o += 128) {
    int f = o / TT, t = o - f*TT;
    s_w[t*TT + f] = fcw[o];
  }
  __syncthreads();

  for (int o = tid; o < CC*TT; o += 128) {
    int c = o / TT, f = o - c*TT;
    const float* cr = s_comb + c*CPAD;
    float a0 = 0.f, a1 = 0.f;
    for (int t = 0; t < TT; t += 2) {
      a0 += cr[t    ] * s_w[(t    )*TT + f];
      a1 += cr[t + 1] * s_w[(t + 1)*TT + f];
    }
    out[bb + o] = tanhf(a0 + a1 + fcb[f]);
  }
}

// ---------------------------------------------------------------- launch
extern "C" void kernel_launch(void* const* d_in, const int* in_sizes, int n_in,
                              void* d_out, int out_size, void* d_ws, size_t ws_size,
                              hipStream_t stream) {
  const float* x     = (const float*)d_in[0];
  const float* adj   = (const float*)d_in[1];
  const float* sadj  = (const float*)d_in[2];
  const float* tmask = (const float*)d_in[3];
  const float* tadj  = (const float*)d_in[4];
  const float* st_wq = (const float*)d_in[5];  const float* st_bq = (const float*)d_in[6];
  const float* st_wk = (const float*)d_in[7];  const float* st_bk = (const float*)d_in[8];
  const float* st_wv = (const float*)d_in[9];  const float* st_bv = (const float*)d_in[10];
  const float* st_wo = (const float*)d_in[11]; const float* st_bo = (const float*)d_in[12];
  const float* ts_wq = (const float*)d_in[13]; const float* ts_bq = (const float*)d_in[14];
  const float* ts_wk = (const float*)d_in[15]; const float* ts_bk = (const float*)d_in[16];
  const float* ts_wv = (const float*)d_in[17]; const float* ts_bv = (const float*)d_in[18];
  const float* ts_wo = (const float*)d_in[19]; const float* ts_bo = (const float*)d_in[20];
  const float* alpha = (const float*)d_in[21]; const float* beta  = (const float*)d_in[22];
  const float* fcw   = (const float*)d_in[23]; const float* fcb   = (const float*)d_in[24];
  float* out = (float*)d_out;

  const int B = in_sizes[0] / (CC*TT);
  const size_t comb_bytes = (size_t)B * CC * TT * 4;
  const size_t w_bytes    = (size_t)W_TOTAL * 2;
  const size_t spt_bytes  = (size_t)B * SPT_R * SPT_S * 2;
  const size_t tp_bytes   = (size_t)B * TP_R * TP_S * 2;
  const size_t need_plain  = 2*comb_bytes + w_bytes + spt_bytes + tp_bytes;
  const size_t need_atomic =   comb_bytes + w_bytes + spt_bytes + tp_bytes;

  if (ws_size >= need_atomic) {
    const int plain = (ws_size >= need_plain) ? 1 : 0;
    const size_t cbuf = plain ? 2*comb_bytes : comb_bytes;
    float* c1      = (float*)d_ws;                       // plain: [B][T][C]; atomic: comb
    float* c2      = plain ? (float*)((char*)d_ws + comb_bytes) : nullptr;  // [B][C][T]
    bf16*  wsec    = (bf16*)((char*)d_ws + cbuf);
    bf16*  spT_all = (bf16*)((char*)d_ws + cbuf + w_bytes);
    bf16*  tp_all  = spT_all + (size_t)B * SPT_R * SPT_S;

    if (!plain) hipMemsetAsync(c1, 0, comb_bytes, stream);
    // weight pre-transposes (one-off, tiny)
    k_tr<<<(512*128+255)/256, 256, 0, stream>>>(st_wk, wsec + W_STWK, TT, EE, EE, 128);
    k_tr<<<(512*128+255)/256, 256, 0, stream>>>(st_wv, wsec + W_STWV, TT, EE, EE, 128);
    k_tr<<<(512* 96+255)/256, 256, 0, stream>>>(st_wq, wsec + W_STWQ, CC, EE, EE,  96);
    k_tr<<<( 80*512+255)/256, 256, 0, stream>>>(st_wo, wsec + W_STWO, EE, CC,  80, 512);
    k_tr<<<(512* 96+255)/256, 256, 0, stream>>>(ts_wk, wsec + W_TSWK, CC, EE, EE,  96);
    k_tr<<<(512* 96+255)/256, 256, 0, stream>>>(ts_wv, wsec + W_TSWV, CC, EE, EE,  96);
    k_tr<<<(512*128+255)/256, 256, 0, stream>>>(ts_wq, wsec + W_TSWQ, TT, EE, EE, 128);
    k_tr<<<(112*512+255)/256, 256, 0, stream>>>(ts_wo, wsec + W_TSWO, EE, TT, 112, 512);

    k_prep<<<B, 256, 0, stream>>>(x, adj, sadj, tmask, tadj, spT_all, tp_all);
    k_attn<<<B*2, 512, 0, stream>>>(spT_all, tp_all, wsec,
                                    st_bq, st_bv, ts_bq, ts_bv,
                                    plain ? c1 : nullptr, c2,
                                    plain ? nullptr : c1, plain);
    k_epi<<<B, 256, 0, stream>>>(plain ? nullptr : c1, c1, c2, x,
                                 st_bo, ts_bo, alpha, beta, fcw, fcb, out, plain);
  } else {
    k_fused<<<B, 128, 0, stream>>>(x, adj, sadj, tmask, tadj,
                                   st_wq, st_bq, st_wk, st_bk, st_wv, st_bv, st_wo, st_bo,
                                   ts_wq, ts_bq, ts_wk, ts_bk, ts_wv, ts_bv, ts_wo, ts_bo,
                                   alpha, beta, fcw, fcb, out);
  }
}